// Round 10
// baseline (338.328 us; speedup 1.0000x reference)
//
#include <hip/hip_runtime.h>
#include <math.h>

// LDS geometry
#define PSTR 40            // fp16 patch cell stride: 80 B
#define GSTR 35            // gate-exchange row stride (floats)
#define GPL  (64 * GSTR)   // one gate plane: 64 px x GSTR floats

typedef _Float16 half8 __attribute__((ext_vector_type(8)));
typedef float    f32x4 __attribute__((ext_vector_type(4)));

__device__ __forceinline__ float fast_tanh(float v) {
    float e = __expf(2.f * v);
    return 1.f - 2.f / (e + 1.f);
}
__device__ __forceinline__ float hsig(float v) {
    return fminf(fmaxf(0.2f * v + 0.5f, 0.f), 1.f);
}

// Pack weights: Wcx[tap][n][ci<32] from Wx[tap][ci][n]; Wch[tap][n][ci] from Wh[tap][ci][n]
__global__ void prep_w(const float* __restrict__ Wx, const float* __restrict__ Wh,
                       _Float16* __restrict__ Wcx, _Float16* __restrict__ Wch) {
    const int k = blockIdx.x;      // 0..575 = tap*64 + ci
    const int n = threadIdx.x;     // 0..127
    const int tap = k >> 6, ci = k & 63;
    if (ci < 32) Wcx[(tap * 128 + n) * 32 + ci]        = (_Float16)Wx[(tap * 32 + ci) * 128 + n];
    else         Wch[(tap * 128 + n) * 32 + (ci - 32)] = (_Float16)Wh[(tap * 32 + (ci - 32)) * 128 + n];
}

// Parallel pre-pass: xg[z=b*16+t] = conv3x3(x_t, Wx) + bias for ALL 128 images.
// 8192 blocks (32/CU queued). N-split waves (wave w = gate w, 4 m-tiles x 2 n-tiles).
// Output stored fp16 in hstep's per-lane fragment layout: thread tid of tile writes
// 32 halfs at ((z*64+tile)*256+tid)*32: [mt(4)][ntl(2)][r(4)] for px=mt*16+quad*4+r,
// n = w*32 + ntl*16 + l15.
__global__ __launch_bounds__(256, 4)
void xgemm(const float* __restrict__ x, const _Float16* __restrict__ Wcx,
           const float* __restrict__ bias, _Float16* __restrict__ xg)
{
    __shared__ _Float16 xp[100 * PSTR];   // 8 KB: 10x10 halo x 32 x-ch

    const int tid  = threadIdx.x;
    const int lane = tid & 63;
    const int w    = tid >> 6;            // gate
    const int l15  = lane & 15, quad = lane >> 4;
    const int tx = blockIdx.x, ty = blockIdx.y, z = blockIdx.z;   // z = b*16+t
    const int px0 = tx * 8, py0 = ty * 8;
    const int tile = ty * 8 + tx;

    const float* xt = x + ((size_t)z * 4096) * 32;
    for (int i = tid; i < 400; i += 256) {
        const int pos = i >> 2, q = i & 3;
        const int row = pos / 10, col = pos - row * 10;
        const int gy = py0 + row - 1, gx = px0 + col - 1;
        half8 hv = {0, 0, 0, 0, 0, 0, 0, 0};
        if ((unsigned)gy < 64u && (unsigned)gx < 64u) {
            const float* s = xt + ((size_t)(gy * 64 + gx)) * 32 + q * 8;
            const float4 v0 = *(const float4*)s;
            const float4 v1 = *(const float4*)(s + 4);
            hv = (half8){(_Float16)v0.x, (_Float16)v0.y, (_Float16)v0.z, (_Float16)v0.w,
                         (_Float16)v1.x, (_Float16)v1.y, (_Float16)v1.z, (_Float16)v1.w};
        }
        *(half8*)&xp[pos * PSTR + q * 8] = hv;
    }

    const float bi0 = bias[w * 32 + l15];
    const float bi1 = bias[w * 32 + 16 + l15];

    __syncthreads();

    f32x4 acc[4][2];
    #pragma unroll
    for (int mt = 0; mt < 4; ++mt) {
        acc[mt][0] = (f32x4){bi0, bi0, bi0, bi0};
        acc[mt][1] = (f32x4){bi1, bi1, bi1, bi1};
    }

    int pb[4];
    #pragma unroll
    for (int mt = 0; mt < 4; ++mt)        // A-frag row px = mt*16 + l15
        pb[mt] = ((mt * 2 + (l15 >> 3)) * 10 + (l15 & 7)) * PSTR + quad * 8;

    const _Float16* wbx = Wcx + ((size_t)(w * 32 + l15)) * 32 + quad * 8;

    #pragma unroll
    for (int tap = 0; tap < 9; ++tap) {
        const int ky = tap / 3, kx = tap - ky * 3;
        const int toff = (ky * 10 + kx) * PSTR;
        half8 a[4];
        #pragma unroll
        for (int mt = 0; mt < 4; ++mt) a[mt] = *(const half8*)&xp[pb[mt] + toff];
        #pragma unroll
        for (int ntl = 0; ntl < 2; ++ntl) {
            const half8 bf = *(const half8*)(wbx + tap * 4096 + ntl * 512);
            #pragma unroll
            for (int mt = 0; mt < 4; ++mt)
                acc[mt][ntl] = __builtin_amdgcn_mfma_f32_16x16x32_f16(a[mt], bf, acc[mt][ntl], 0, 0, 0);
        }
    }

    // write per-lane fragment-layout xg: 4 x half8 = 64 B contiguous
    _Float16* dst = xg + (((size_t)z * 64 + tile) * 256 + tid) * 32;
    #pragma unroll
    for (int mt = 0; mt < 4; ++mt) {
        half8 o;
        #pragma unroll
        for (int r = 0; r < 4; ++r) { o[r] = (_Float16)acc[mt][0][r]; o[4 + r] = (_Float16)acc[mt][1][r]; }
        *(half8*)(dst + mt * 8) = o;
    }
}

// Sequential step (light): h-conv only. acc init = xg fragment load (bias included).
// r7's N-split structure: wave w = gate w over 64 px; 18 B-frag loads / 36 MFMA per
// wave (t>0). Gates exchanged via padded LDS; epilogue coalesced. Grid (8,8,8).
__global__ __launch_bounds__(256, 2)
void hstep(const _Float16* __restrict__ xg, const _Float16* __restrict__ Wch,
           const float* __restrict__ gamma_, const float* __restrict__ beta_,
           const float* __restrict__ mmean, const float* __restrict__ mvar,
           const _Float16* __restrict__ hprev, _Float16* __restrict__ hnext,
           float* __restrict__ csw, float* __restrict__ out, int t)
{
    __shared__ _Float16 hp[100 * PSTR];   // 8 KB: 10x10 halo x 32 h-ch
    __shared__ float    glds[4 * GPL];    // 35 KB: gate exchange [gate][px][f]

    const int tid  = threadIdx.x;
    const int lane = tid & 63;
    const int w    = tid >> 6;            // gate
    const int l15  = lane & 15, quad = lane >> 4;
    const int b = blockIdx.x, tx = blockIdx.y, ty = blockIdx.z;
    const int px0 = tx * 8, py0 = ty * 8;
    const int tile = ty * 8 + tx;

    // ---- stage h patch (fp16), t>0 only ----
    if (t > 0) {
        const _Float16* hb = hprev + (size_t)b * 4096 * 32;
        for (int i = tid; i < 400; i += 256) {
            const int pos = i >> 2, q = i & 3;
            const int row = pos / 10, col = pos - row * 10;
            const int gy = py0 + row - 1, gx = px0 + col - 1;
            half8 hv = {0, 0, 0, 0, 0, 0, 0, 0};
            if ((unsigned)gy < 64u && (unsigned)gx < 64u)
                hv = *(const half8*)(hb + ((size_t)(gy * 64 + gx)) * 32 + q * 8);
            *(half8*)&hp[pos * PSTR + q * 8] = hv;
        }
    }

    // ---- xg fragment load: 64 B contiguous per lane (issue early) ----
    const _Float16* xgp = xg + (((size_t)(b * 16 + t) * 64 + tile) * 256 + tid) * 32;
    half8 xv[4];
    #pragma unroll
    for (int mt = 0; mt < 4; ++mt) xv[mt] = *(const half8*)(xgp + mt * 8);

    __syncthreads();

    // ---- acc init from xg; h-conv MFMA (t>0) ----
    f32x4 acc[4][2];
    #pragma unroll
    for (int mt = 0; mt < 4; ++mt)
        #pragma unroll
        for (int ntl = 0; ntl < 2; ++ntl)
            #pragma unroll
            for (int r = 0; r < 4; ++r)
                acc[mt][ntl][r] = (float)xv[mt][ntl * 4 + r];

    if (t > 0) {
        int pb[4];
        #pragma unroll
        for (int mt = 0; mt < 4; ++mt)
            pb[mt] = ((mt * 2 + (l15 >> 3)) * 10 + (l15 & 7)) * PSTR + quad * 8;
        const _Float16* wbh = Wch + ((size_t)(w * 32 + l15)) * 32 + quad * 8;
        #pragma unroll
        for (int tap = 0; tap < 9; ++tap) {
            const int ky = tap / 3, kx = tap - ky * 3;
            const int toff = (ky * 10 + kx) * PSTR;
            half8 a[4];
            #pragma unroll
            for (int mt = 0; mt < 4; ++mt) a[mt] = *(const half8*)&hp[pb[mt] + toff];
            #pragma unroll
            for (int ntl = 0; ntl < 2; ++ntl) {
                const half8 bf = *(const half8*)(wbh + tap * 4096 + ntl * 512);
                #pragma unroll
                for (int mt = 0; mt < 4; ++mt)
                    acc[mt][ntl] = __builtin_amdgcn_mfma_f32_16x16x32_f16(a[mt], bf, acc[mt][ntl], 0, 0, 0);
            }
        }
    }

    // ---- write gate plane to LDS: glds[w][px][f] ----
    #pragma unroll
    for (int mt = 0; mt < 4; ++mt)
        #pragma unroll
        for (int ntl = 0; ntl < 2; ++ntl)
            #pragma unroll
            for (int r = 0; r < 4; ++r) {
                const int px = mt * 16 + quad * 4 + r;
                glds[w * GPL + px * GSTR + ntl * 16 + l15] = acc[mt][ntl][r];
            }

    __syncthreads();

    // ---- epilogue: thread owns (px = tid>>2, f = f0..f0+7), coalesced I/O ----
    const int pxt = tid >> 2, f0 = (tid & 3) * 8;
    const int gy = py0 + (pxt >> 3), gx = px0 + (pxt & 7);

    float gav[8], bev[8], mmv[8], mvv[8];
    *(float4*)&gav[0] = *(const float4*)&gamma_[f0];
    *(float4*)&gav[4] = *(const float4*)&gamma_[f0 + 4];
    *(float4*)&bev[0] = *(const float4*)&beta_[f0];
    *(float4*)&bev[4] = *(const float4*)&beta_[f0 + 4];
    *(float4*)&mmv[0] = *(const float4*)&mmean[f0];
    *(float4*)&mmv[4] = *(const float4*)&mmean[f0 + 4];
    *(float4*)&mvv[0] = *(const float4*)&mvar[f0];
    *(float4*)&mvv[4] = *(const float4*)&mvar[f0 + 4];

    float* cp = csw + (((size_t)b * 64 + tile) * 256 + tid) * 8;
    float cov[8];
    #pragma unroll
    for (int j = 0; j < 8; ++j) cov[j] = 0.f;
    if (t > 0) {
        *(f32x4*)&cov[0] = *(const f32x4*)cp;
        *(f32x4*)&cov[4] = *(const f32x4*)(cp + 4);
    }

    const int gb = pxt * GSTR + f0;
    half8 hv8;
    float ov[8], cnv[8];
    #pragma unroll
    for (int j = 0; j < 8; ++j) {
        const float gi = glds[0 * GPL + gb + j];
        const float gf = glds[1 * GPL + gb + j];
        const float gc = glds[2 * GPL + gb + j];
        const float go = glds[3 * GPL + gb + j];
        const float inv = gav[j] * rsqrtf(mvv[j] + 1e-3f);
        const float bnb = bev[j] - mmv[j] * inv;
        const float cn = hsig(gf) * cov[j] + hsig(gi) * fast_tanh(gc);
        const float hh = hsig(go) * fast_tanh(cn);
        cnv[j] = cn;
        hv8[j] = (_Float16)hh;
        ov[j] = hh * inv + bnb;
    }

    const size_t pix = ((size_t)(gy * 64 + gx)) * 32 + f0;
    float* oq = out + (((size_t)b * 16 + t) * 4096) * 32;
    *(float4*)(oq + pix)     = *(float4*)&ov[0];  // 2 x 16 B coalesced
    *(float4*)(oq + pix + 4) = *(float4*)&ov[4];
    if (t < 15) {                                  // h_15 / c_15 never consumed
        _Float16* hq = hnext + (size_t)b * 4096 * 32;
        *(half8*)(hq + pix) = hv8;                 // 16 B coalesced
        *(f32x4*)cp       = *(f32x4*)&cnv[0];      // 2 x 16 B coalesced
        *(f32x4*)(cp + 4) = *(f32x4*)&cnv[4];
    }
}

extern "C" void kernel_launch(void* const* d_in, const int* in_sizes, int n_in,
                              void* d_out, int out_size, void* d_ws, size_t ws_size,
                              hipStream_t stream)
{
    const float* x      = (const float*)d_in[0];
    const float* Wx     = (const float*)d_in[1];
    const float* Wh     = (const float*)d_in[2];
    const float* bias   = (const float*)d_in[3];
    const float* gamma_ = (const float*)d_in[4];
    const float* beta_  = (const float*)d_in[5];
    const float* mmean  = (const float*)d_in[6];
    const float* mvar   = (const float*)d_in[7];
    float* out = (float*)d_out;

    // ws: [h0 2MB][h1 2MB][csw 4MB][xg 128MB][Wcx 72KB][Wch 72KB] = 136.1 MB
    char* wsb = (char*)d_ws;
    _Float16* h0  = (_Float16*)(wsb);
    _Float16* h1  = (_Float16*)(wsb + (1 << 21));
    float*    csw = (float*)(wsb + (1 << 22));
    _Float16* xg  = (_Float16*)(wsb + (1 << 23));
    _Float16* Wcx = (_Float16*)(wsb + (1 << 23) + (1 << 27));
    _Float16* Wch = (_Float16*)(wsb + (1 << 23) + (1 << 27) + 73728);

    prep_w<<<dim3(576), dim3(128), 0, stream>>>(Wx, Wh, Wcx, Wch);

    // One parallel x-conv pass over all 128 (b,t) images.
    xgemm<<<dim3(8, 8, 128), 256, 0, stream>>>(x, Wcx, bias, xg);

    // 16 light sequential h-steps. No memset: t=0 skips h-conv and starts c=0.
    _Float16* hpr = h0;
    _Float16* hnx = h1;
    for (int t = 0; t < 16; ++t) {
        hstep<<<dim3(8, 8, 8), 256, 0, stream>>>(
            xg, Wch, gamma_, beta_, mmean, mvar, hpr, hnx, csw, out, t);
        _Float16* tmp = hpr; hpr = hnx; hnx = tmp;
    }
}

// Round 11
// 295.864 us; speedup vs baseline: 1.1435x; 1.1435x over previous
//
#include <hip/hip_runtime.h>
#include <math.h>

// LDS geometry: 16x8 px tile, 10x18 halo patch
#define PSTR 40             // fp16 patch cell stride: 80 B
#define GSTR 33             // gate-exchange px stride (floats, +1 pad)
#define GPL  (128 * GSTR)   // one gate plane: 128 px x GSTR floats

typedef _Float16 half8 __attribute__((ext_vector_type(8)));
typedef float    f32x4 __attribute__((ext_vector_type(4)));

__device__ __forceinline__ float fast_tanh(float v) {
    float e = __expf(2.f * v);
    return 1.f - 2.f / (e + 1.f);
}
__device__ __forceinline__ float hsig(float v) {
    return fminf(fmaxf(0.2f * v + 0.5f, 0.f), 1.f);
}
__device__ __forceinline__ int div18(int c) { return (c * 57) >> 10; }  // c <= 180

// Pack weights: Wcx[tap][n][ci<32] from Wx[tap][ci][n]; Wch[tap][n][ci] from Wh[tap][ci][n]
__global__ void prep_w(const float* __restrict__ Wx, const float* __restrict__ Wh,
                       _Float16* __restrict__ Wcx, _Float16* __restrict__ Wch) {
    const int k = blockIdx.x;      // 0..575 = tap*64 + ci
    const int n = threadIdx.x;     // 0..127
    const int tap = k >> 6, ci = k & 63;
    if (ci < 32) Wcx[(tap * 128 + n) * 32 + ci]        = (_Float16)Wx[(tap * 32 + ci) * 128 + n];
    else         Wch[(tap * 128 + n) * 32 + (ci - 32)] = (_Float16)Wh[(tap * 32 + (ci - 32)) * 128 + n];
}

// One fused timestep per launch. FAT blocks: 16x8 px tile, 512 threads (8 waves),
// 256 blocks = 1/CU. Wave (g=w&3, mtg=w>>2): gate g over 64 px (4 m-tiles, rows
// mtg*4..+3). 36 B-frag loads feed 144 MFMA (8x reuse); 16 independent acc chains
// give per-wave ILP. Gates exchanged via fp32 LDS; epilogue coalesced.
// Grid (8,4,8): blockIdx.x = batch (all tiles of batch b land on XCD b).
__global__ __launch_bounds__(512, 2)
void lstm_step_k(const float* __restrict__ x, const _Float16* __restrict__ Wcx,
                 const _Float16* __restrict__ Wch, const float* __restrict__ bias,
                 const float* __restrict__ gamma_, const float* __restrict__ beta_,
                 const float* __restrict__ mmean, const float* __restrict__ mvar,
                 const _Float16* __restrict__ hprev, _Float16* __restrict__ hnext,
                 float* __restrict__ csw, float* __restrict__ out, int t)
{
    __shared__ _Float16 xp[180 * PSTR];   // 14.4 KB: 10x18 halo x 32 x-ch
    __shared__ _Float16 hp[180 * PSTR];   // 14.4 KB: 10x18 halo x 32 h-ch
    __shared__ float    glds[4 * GPL];    // 67.6 KB: gate exchange [gate][px][f]

    const int tid  = threadIdx.x;         // 0..511
    const int lane = tid & 63;
    const int w    = tid >> 6;            // 0..7
    const int l15  = lane & 15, quad = lane >> 4;
    const int g    = w & 3, mtg = w >> 2; // gate, px-half
    const int b = blockIdx.x, tx = blockIdx.y, ty = blockIdx.z;
    const int px0 = tx * 16, py0 = ty * 8;
    const int tile = ty * 4 + tx;         // 0..31

    // ---- stage x patch (fp32 -> fp16) and h patch (fp16): 720 items over 512 thr ----
    const float* xt = x + (((size_t)b * 16 + t) * 4096) * 32;
    for (int i = tid; i < 720; i += 512) {
        const int cell = i >> 2, q = i & 3;
        const int row = div18(cell), col = cell - row * 18;
        const int gy = py0 + row - 1, gx = px0 + col - 1;
        half8 hv = {0, 0, 0, 0, 0, 0, 0, 0};
        if ((unsigned)gy < 64u && (unsigned)gx < 64u) {
            const float* s = xt + ((size_t)(gy * 64 + gx)) * 32 + q * 8;
            const float4 v0 = *(const float4*)s;
            const float4 v1 = *(const float4*)(s + 4);
            hv = (half8){(_Float16)v0.x, (_Float16)v0.y, (_Float16)v0.z, (_Float16)v0.w,
                         (_Float16)v1.x, (_Float16)v1.y, (_Float16)v1.z, (_Float16)v1.w};
        }
        *(half8*)&xp[cell * PSTR + q * 8] = hv;
    }
    if (t > 0) {
        const _Float16* hb = hprev + (size_t)b * 4096 * 32;
        for (int i = tid; i < 720; i += 512) {
            const int cell = i >> 2, q = i & 3;
            const int row = div18(cell), col = cell - row * 18;
            const int gy = py0 + row - 1, gx = px0 + col - 1;
            half8 hv = {0, 0, 0, 0, 0, 0, 0, 0};
            if ((unsigned)gy < 64u && (unsigned)gx < 64u)
                hv = *(const half8*)(hb + ((size_t)(gy * 64 + gx)) * 32 + q * 8);
            *(half8*)&hp[cell * PSTR + q * 8] = hv;
        }
    }

    // bias for this wave's gate: n = g*32 + ntl*16 + l15
    const float bi0 = bias[g * 32 + l15];
    const float bi1 = bias[g * 32 + 16 + l15];

    __syncthreads();

    // ---- MFMA: acc[mi][ntl]; m-tile = row mtg*4+mi; px = m*16 + quad*4 + r ----
    f32x4 acc[4][2];
    #pragma unroll
    for (int mi = 0; mi < 4; ++mi) {
        acc[mi][0] = (f32x4){bi0, bi0, bi0, bi0};
        acc[mi][1] = (f32x4){bi1, bi1, bi1, bi1};
    }

    int pb[4];
    #pragma unroll
    for (int mi = 0; mi < 4; ++mi)        // A-frag: row m, col l15 -> patch cell
        pb[mi] = ((mtg * 4 + mi) * 18 + l15) * PSTR + quad * 8;

    const _Float16* wbx = Wcx + ((size_t)(g * 32 + l15)) * 32 + quad * 8;
    const _Float16* wbh = Wch + ((size_t)(g * 32 + l15)) * 32 + quad * 8;

    #pragma unroll
    for (int tap = 0; tap < 9; ++tap) {
        const int ky = tap / 3, kx = tap - ky * 3;
        const int toff = (ky * 18 + kx) * PSTR;
        half8 a[4];
        #pragma unroll
        for (int mi = 0; mi < 4; ++mi) a[mi] = *(const half8*)&xp[pb[mi] + toff];
        #pragma unroll
        for (int ntl = 0; ntl < 2; ++ntl) {
            const half8 bf = *(const half8*)(wbx + tap * 4096 + ntl * 512);
            #pragma unroll
            for (int mi = 0; mi < 4; ++mi)
                acc[mi][ntl] = __builtin_amdgcn_mfma_f32_16x16x32_f16(a[mi], bf, acc[mi][ntl], 0, 0, 0);
        }
    }
    if (t > 0) {
        #pragma unroll
        for (int tap = 0; tap < 9; ++tap) {
            const int ky = tap / 3, kx = tap - ky * 3;
            const int toff = (ky * 18 + kx) * PSTR;
            half8 a[4];
            #pragma unroll
            for (int mi = 0; mi < 4; ++mi) a[mi] = *(const half8*)&hp[pb[mi] + toff];
            #pragma unroll
            for (int ntl = 0; ntl < 2; ++ntl) {
                const half8 bf = *(const half8*)(wbh + tap * 4096 + ntl * 512);
                #pragma unroll
                for (int mi = 0; mi < 4; ++mi)
                    acc[mi][ntl] = __builtin_amdgcn_mfma_f32_16x16x32_f16(a[mi], bf, acc[mi][ntl], 0, 0, 0);
            }
        }
    }

    // ---- write this wave's gate planes to LDS: glds[g][px][f] ----
    #pragma unroll
    for (int mi = 0; mi < 4; ++mi)
        #pragma unroll
        for (int ntl = 0; ntl < 2; ++ntl)
            #pragma unroll
            for (int r = 0; r < 4; ++r) {
                const int px = (mtg * 4 + mi) * 16 + quad * 4 + r;
                glds[g * GPL + px * GSTR + ntl * 16 + l15] = acc[mi][ntl][r];
            }

    __syncthreads();

    // ---- epilogue: thread owns (px = tid>>2, f = f0..f0+7), coalesced I/O ----
    const int pxt = tid >> 2, f0 = (tid & 3) * 8;
    const int gy = py0 + (pxt >> 4), gx = px0 + (pxt & 15);

    float gav[8], bev[8], mmv[8], mvv[8];
    *(float4*)&gav[0] = *(const float4*)&gamma_[f0];
    *(float4*)&gav[4] = *(const float4*)&gamma_[f0 + 4];
    *(float4*)&bev[0] = *(const float4*)&beta_[f0];
    *(float4*)&bev[4] = *(const float4*)&beta_[f0 + 4];
    *(float4*)&mmv[0] = *(const float4*)&mmean[f0];
    *(float4*)&mmv[4] = *(const float4*)&mmean[f0 + 4];
    *(float4*)&mvv[0] = *(const float4*)&mvar[f0];
    *(float4*)&mvv[4] = *(const float4*)&mvar[f0 + 4];

    float* cp = csw + (((size_t)b * 32 + tile) * 512 + tid) * 8;
    float cov[8];
    #pragma unroll
    for (int j = 0; j < 8; ++j) cov[j] = 0.f;
    if (t > 0) {
        *(f32x4*)&cov[0] = *(const f32x4*)cp;
        *(f32x4*)&cov[4] = *(const f32x4*)(cp + 4);
    }

    const int gb = pxt * GSTR + f0;
    half8 hv8;
    float ov[8], cnv[8];
    #pragma unroll
    for (int j = 0; j < 8; ++j) {
        const float gi = glds[0 * GPL + gb + j];
        const float gf = glds[1 * GPL + gb + j];
        const float gc = glds[2 * GPL + gb + j];
        const float go = glds[3 * GPL + gb + j];
        const float inv = gav[j] * rsqrtf(mvv[j] + 1e-3f);
        const float bnb = bev[j] - mmv[j] * inv;
        const float cn = hsig(gf) * cov[j] + hsig(gi) * fast_tanh(gc);
        const float hh = hsig(go) * fast_tanh(cn);
        cnv[j] = cn;
        hv8[j] = (_Float16)hh;
        ov[j] = hh * inv + bnb;
    }

    const size_t pix = ((size_t)(gy * 64 + gx)) * 32 + f0;
    float* oq = out + (((size_t)b * 16 + t) * 4096) * 32;
    *(float4*)(oq + pix)     = *(float4*)&ov[0];  // 2 x 16 B coalesced
    *(float4*)(oq + pix + 4) = *(float4*)&ov[4];
    if (t < 15) {                                  // h_15 / c_15 never consumed
        _Float16* hq = hnext + (size_t)b * 4096 * 32;
        *(half8*)(hq + pix) = hv8;                 // 16 B coalesced
        *(f32x4*)cp       = *(f32x4*)&cnv[0];      // 2 x 16 B coalesced
        *(f32x4*)(cp + 4) = *(f32x4*)&cnv[4];
    }
}

extern "C" void kernel_launch(void* const* d_in, const int* in_sizes, int n_in,
                              void* d_out, int out_size, void* d_ws, size_t ws_size,
                              hipStream_t stream)
{
    const float* x      = (const float*)d_in[0];
    const float* Wx     = (const float*)d_in[1];
    const float* Wh     = (const float*)d_in[2];
    const float* bias   = (const float*)d_in[3];
    const float* gamma_ = (const float*)d_in[4];
    const float* beta_  = (const float*)d_in[5];
    const float* mmean  = (const float*)d_in[6];
    const float* mvar   = (const float*)d_in[7];
    float* out = (float*)d_out;

    // ws: [h0 2MB][h1 2MB][csw 4MB][Wcx 72KB][Wch 72KB]
    char* wsb = (char*)d_ws;
    _Float16* h0  = (_Float16*)(wsb);
    _Float16* h1  = (_Float16*)(wsb + (1 << 21));
    float*    csw = (float*)(wsb + (1 << 22));
    _Float16* Wcx = (_Float16*)(wsb + (1 << 23));
    _Float16* Wch = (_Float16*)(wsb + (1 << 23) + 73728);

    prep_w<<<dim3(576), dim3(128), 0, stream>>>(Wx, Wh, Wcx, Wch);

    // 16 fat fused-step launches. No memset: t=0 skips h-conv and starts c=0.
    _Float16* hpr = h0;
    _Float16* hnx = h1;
    for (int t = 0; t < 16; ++t) {
        lstm_step_k<<<dim3(8, 4, 8), 512, 0, stream>>>(
            x, Wcx, Wch, bias, gamma_, beta_, mmean, mvar, hpr, hnx, csw, out, t);
        _Float16* tmp = hpr; hpr = hnx; hnx = tmp;
    }
}